// Round 10
// baseline (183.461 us; speedup 1.0000x reference)
//
#include <hip/hip_runtime.h>
#include <hip/hip_bf16.h>

// KroneckerAttention on MI355X.
// B=2,H=16 (BH=32), NQ=NK=4096, D=64, m=n=4, pq=pk=1024, c0=c1=2, scale=1/8.
//
// ws layout:
//   floats [0,512)    : nsq[bh][gi][gj]    (atomicAdd partials, memset to 0)
//   floats [512,8704) : vsum[bh][gj][dd]   (atomicAdd partials, memset to 0)
//   bytes  [34816, +4MB)  : Qb  bf16 16x16x32 B-frags, pre-scaled 0.125*log2e
//   bytes  [+4MB, +8MB)   : Kb  bf16 16x16x32 A-frags (central key group)
//   bytes  [+8MB, +24MB)  : Vb  f16  16x16x32 B-frags (all value rows)
//
// v10: TLP experiment, properly this time. R9 showed the residency cap was
// the GRID (1024 = 4 blocks/CU exactly), not LDS. Halve the q-tile to 16
// rows (1 MFMA tile) -> grid 2048 -> 8 blocks/CU schedulable. LDS ~8.5KB,
// VGPR ~50 (no launch_bounds cap — R8 lesson: the bound CAPS the allocator).
// Work conserved; the per-block serial chain is hidden by 2x resident blocks.
// Known bound: V-frag L2 traffic doubles to ~1GB -> ~29us L2 floor.

#define BH_TOT 32
#define SEQ    4096
#define DIM    64
#define PQ     1024

#define QB_OFF 34816u
#define KB_OFF (QB_OFF + 4u*1024u*1024u)
#define VB_OFF (KB_OFF + 4u*1024u*1024u)
#define WS_NEED (VB_OFF + 16u*1024u*1024u)

#define QSCALE 0.1803368801111204f   // 0.125 * log2(e)

typedef __attribute__((ext_vector_type(8))) short bf16x8;
typedef __attribute__((ext_vector_type(4))) short bf16x4;
typedef __attribute__((ext_vector_type(4))) float f32x4;
typedef __attribute__((ext_vector_type(4))) _Float16 f16x4;
typedef __attribute__((ext_vector_type(8))) _Float16 f16x8;

__device__ __forceinline__ short f2bf(float x) {
    unsigned u = __float_as_uint(x);
    u = u + 0x7fffu + ((u >> 16) & 1u);   // RNE truncate to bf16
    return (short)(u >> 16);
}
__device__ __forceinline__ float bf2f(unsigned short h) {
    return __uint_as_float(((unsigned)h) << 16);
}

// ---------------- mega_prep: grid 3584 (unchanged) -------------------------
// [0,512)     : norm partials (bh,gi,chunk of 256 q rows) -> atomicAdd nsq
// [512,2560)  : V f16 frags + vsum atomic partials (bh,gj,kc)
// [2560,3072) : Q bf16 frags (pre-scaled)
// [3072,3584) : K bf16 frags (central group)
__global__ __launch_bounds__(256) void mega_prep(
    const float* __restrict__ query, const float* __restrict__ key,
    const float* __restrict__ value, float* __restrict__ ws,
    char* __restrict__ wsb)
{
    __shared__ union {
        struct { float ksm[4][64]; float wsum[4][16]; } n;
        struct { float Ls[64][68]; float ps[4][64]; } v;
    } sm;
    const int t = threadIdx.x;
    const int bid = blockIdx.x;

    if (bid < 512) {
        // ---- norm: w = Q @ k_sample^T, nsq[gi][gj] += sum_q w^2 (256 rows)
        const int bh = bid >> 4, gi = (bid >> 2) & 3, chunk = bid & 3;
        sm.n.ksm[t >> 6][t & 63] =
            key[((size_t)bh * SEQ + (size_t)(t >> 6) * PQ) * DIM + (t & 63)];
        __syncthreads();
        const int wv = t >> 6, lane = t & 63, c = lane & 15, hi = lane >> 4;
        bf16x8 bb0, bb1;
#pragma unroll
        for (int j = 0; j < 8; ++j) {
            bb0[j] = (c < 4) ? f2bf(sm.n.ksm[c][hi * 8 + j]) : (short)0;
            bb1[j] = (c < 4) ? f2bf(sm.n.ksm[c][32 + hi * 8 + j]) : (short)0;
        }
        float acc0 = 0.f, acc1 = 0.f, acc2 = 0.f, acc3 = 0.f;
        const float* qbase = query +
            ((size_t)bh * SEQ + (size_t)gi * PQ + (size_t)chunk * 256) * DIM;
#pragma unroll
        for (int it = 0; it < 4; ++it) {
            const int row = (wv * 4 + it) * 16 + c;
            const float* qp = qbase + (size_t)row * 64 + hi * 8;
            float4 a0 = *(const float4*)qp;
            float4 a1 = *(const float4*)(qp + 4);
            float4 a2 = *(const float4*)(qp + 32);
            float4 a3 = *(const float4*)(qp + 36);
            bf16x8 qa0, qa1;
            qa0[0] = f2bf(a0.x); qa0[1] = f2bf(a0.y); qa0[2] = f2bf(a0.z); qa0[3] = f2bf(a0.w);
            qa0[4] = f2bf(a1.x); qa0[5] = f2bf(a1.y); qa0[6] = f2bf(a1.z); qa0[7] = f2bf(a1.w);
            qa1[0] = f2bf(a2.x); qa1[1] = f2bf(a2.y); qa1[2] = f2bf(a2.z); qa1[3] = f2bf(a2.w);
            qa1[4] = f2bf(a3.x); qa1[5] = f2bf(a3.y); qa1[6] = f2bf(a3.z); qa1[7] = f2bf(a3.w);
            f32x4 s = (f32x4){0.f, 0.f, 0.f, 0.f};
            s = __builtin_amdgcn_mfma_f32_16x16x32_bf16(qa0, bb0, s, 0, 0, 0);
            s = __builtin_amdgcn_mfma_f32_16x16x32_bf16(qa1, bb1, s, 0, 0, 0);
            acc0 += s[0] * s[0]; acc1 += s[1] * s[1];
            acc2 += s[2] * s[2]; acc3 += s[3] * s[3];
        }
        float asum = acc0 + acc1 + acc2 + acc3;
        asum += __shfl_xor(asum, 16);
        asum += __shfl_xor(asum, 32);
        if (lane < 16) sm.n.wsum[wv][lane] = asum;
        __syncthreads();
        if (t < 4)
            atomicAdd(&ws[bh * 16 + gi * 4 + t],
                      sm.n.wsum[0][t] + sm.n.wsum[1][t] + sm.n.wsum[2][t] + sm.n.wsum[3][t]);
    } else if (bid < 2560) {
        // ---- conv_v: (bh,gj,kc) -> f16 B-frags + vsum atomic partial
        const int blk = bid - 512;
        const int bh = blk >> 6, gj = (blk >> 4) & 3, kc = blk & 15;
        const float* src = value + ((size_t)bh * SEQ + gj * PQ + kc * 64) * DIM;
#pragma unroll
        for (int i = 0; i < 4; ++i) {
            const int u = t + i * 256;
            const int row = u >> 4, c4 = (u & 15) * 4;
            *(float4*)&sm.v.Ls[row][c4] = *(const float4*)(src + row * 64 + c4);
        }
        __syncthreads();
        {
            const int d = t & 63, rg = t >> 6;
            float s = 0.f;
#pragma unroll
            for (int i = 0; i < 16; ++i) s += sm.v.Ls[rg * 16 + i][d];
            sm.v.ps[rg][d] = s;
        }
        __syncthreads();
        if (t < 64) {
            float tot = sm.v.ps[0][t] + sm.v.ps[1][t] + sm.v.ps[2][t] + sm.v.ps[3][t];
            atomicAdd(&ws[512 + bh * 256 + gj * 64 + t], tot);
        }
        // 16x16x32 f16 B-frags: lane(c,hi) holds V[span*32 + hi*8 + j][dt*16 + c]
#pragma unroll
        for (int i = 0; i < 2; ++i) {
            const int sid = t + i * 256;
            const int pl = sid >> 8, dt = (sid >> 6) & 3, lane = sid & 63;
            const int c = lane & 15, hi = lane >> 4;
            f16x8 h;
#pragma unroll
            for (int j = 0; j < 8; ++j)
                h[j] = (_Float16)sm.v.Ls[pl * 32 + hi * 8 + j][dt * 16 + c];
            const size_t off = ((((size_t)(bh * 4 + gj) * 32 + kc * 2 + pl) * 4 + dt) * 64 + lane) * 16;
            *(f16x8*)(wsb + VB_OFF + off) = h;
        }
    } else if (bid < 3072) {
        // ---- Q frags (pre-scaled by 0.125*log2e)
        const int qb = bid - 2560;
        const int bh = qb >> 4, qt = qb & 15;
#pragma unroll
        for (int i = 0; i < 2; ++i) {
            const int sid = t + i * 256;
            const int mt = sid >> 7, kh = (sid >> 6) & 1, lane = sid & 63;
            const int c = lane & 15, hi = lane >> 4;
            const float* p = query + ((size_t)bh * SEQ + 2048 + qt * 64 + mt * 16 + c) * DIM
                             + kh * 32 + hi * 8;
            float4 a = *(const float4*)p, b = *(const float4*)(p + 4);
            bf16x8 h;
            h[0] = f2bf(a.x * QSCALE); h[1] = f2bf(a.y * QSCALE);
            h[2] = f2bf(a.z * QSCALE); h[3] = f2bf(a.w * QSCALE);
            h[4] = f2bf(b.x * QSCALE); h[5] = f2bf(b.y * QSCALE);
            h[6] = f2bf(b.z * QSCALE); h[7] = f2bf(b.w * QSCALE);
            const size_t fidx = ((size_t)(bh * 16 + qt) * 4 + mt) * 2 + kh;
            *(bf16x8*)(wsb + QB_OFF + fidx * 1024 + lane * 16) = h;
        }
    } else {
        // ---- K frags (central group)
        const int b2 = bid - 3072;
        const int bh = b2 >> 4, kc = b2 & 15;
#pragma unroll
        for (int i = 0; i < 2; ++i) {
            const int sid = t + i * 256;
            const int kh = sid >> 8, nt = (sid >> 6) & 3, lane = sid & 63;
            const int c = lane & 15, hi = lane >> 4;
            const float* p = key + ((size_t)bh * SEQ + 2048 + kc * 64 + nt * 16 + c) * DIM
                             + kh * 32 + hi * 8;
            float4 a = *(const float4*)p, b = *(const float4*)(p + 4);
            bf16x8 h;
            h[0] = f2bf(a.x); h[1] = f2bf(a.y); h[2] = f2bf(a.z); h[3] = f2bf(a.w);
            h[4] = f2bf(b.x); h[5] = f2bf(b.y); h[6] = f2bf(b.z); h[7] = f2bf(b.w);
            const size_t fidx = ((size_t)(bh * 16 + kc) * 2 + kh) * 4 + nt;
            *(bf16x8*)(wsb + KB_OFF + fidx * 1024 + lane * 16) = h;
        }
    }
}

// ---------------- kattn4 v10: 16-q blocks, grid 2048, XCD-swizzled ---------
// block = 256 (4 waves). Each block: 16 q rows x 1024 keys. Per kc: wave w
// computes S^T for its 16 keys x 16 q (2 MFMA), P -> 2-span LDS, PV for its
// gj group (10 MFMA). 8 blocks/CU schedulable (LDS ~8.5KB, VGPR ~50).
__global__ __launch_bounds__(256, 4) void kattn4(
    const char* __restrict__ wsb, float* __restrict__ out)
{
    __shared__ union {
        _Float16 Pf[2][2][512];        // [buf][span][frag] — 4 KB
        unsigned short Ub[16][260];    // epilogue: bf16 U — 8.3 KB
    } lds;
    __shared__ float Llds[16];

    const int blk = blockIdx.x;
    const int slot = blk >> 3;                    // 0..255
    const int bh = (blk & 7) * 4 + (slot >> 6);   // XCD-major: all of bh on one XCD
    const int qt16 = slot & 63;                   // 16-row tile
    const int t = threadIdx.x;
    const int w = t >> 6, lane = t & 63;
    const int c = lane & 15, hi = lane >> 4;

    // Q B-frags (pre-scaled): strip s = qt16
    bf16x8 aq0, aq1;
    {
        const size_t fr = ((size_t)(bh * 16 + (qt16 >> 2)) * 4 + (qt16 & 3)) * 2;
        aq0 = *(const bf16x8*)(wsb + QB_OFF + fr * 1024 + lane * 16);
        aq1 = *(const bf16x8*)(wsb + QB_OFF + (fr + 1) * 1024 + lane * 16);
    }
    const char* kb = wsb + KB_OFF + ((size_t)(bh * 16) * 8) * 1024 + (size_t)w * 1024 + lane * 16;
    const char* vb = wsb + VB_OFF + ((size_t)(bh * 4 + w) * 128) * 1024 + lane * 16;

    f32x4 Uacc[4];
#pragma unroll
    for (int dt = 0; dt < 4; ++dt)
        Uacc[dt] = (f32x4){0.f, 0.f, 0.f, 0.f};
    f32x4 Lacc = (f32x4){0.f, 0.f, 0.f, 0.f};
    f16x8 kOnes;
#pragma unroll
    for (int j = 0; j < 8; ++j) kOnes[j] = (_Float16)1.f;

    // P write coords (A-frag order): element (m=c, k=w*16+hi*4+r)
    const int k0 = w * 16 + hi * 4;
    const int pspan = k0 >> 5;                    // w>>1
    const int pidx = (c + 16 * ((k0 & 31) >> 3)) * 8 + (k0 & 7);  // b64 dest

    bf16x8 bk0 = *(const bf16x8*)(kb);
    bf16x8 bk1 = *(const bf16x8*)(kb + 4096);

    for (int kc = 0; kc < 16; ++kc) {
        const int buf = kc & 1;
        // ---- V(kc) loads first: consumed after the barrier; S + exp2/pack
        // + barrier cover their L2 latency.
        const char* vcb = vb + (size_t)kc * 8192;
        f16x8 vf[8];
#pragma unroll
        for (int u = 0; u < 8; ++u) vf[u] = *(const f16x8*)(vcb + u * 1024);
        // ---- S^T strip: A = this wave's 16 keys, B = 16 q (1 tile)
        f32x4 sacc;
        __builtin_amdgcn_s_setprio(1);
        {
            f32x4 s = (f32x4){0.f, 0.f, 0.f, 0.f};
            s = __builtin_amdgcn_mfma_f32_16x16x32_bf16(bk0, aq0, s, 0, 0, 0);
            s = __builtin_amdgcn_mfma_f32_16x16x32_bf16(bk1, aq1, s, 0, 0, 0);
            sacc = s;
        }
        __builtin_amdgcn_s_setprio(0);
        // ---- prefetch K(kc+1); stays in flight across the barrier (counted)
        if (kc < 15) {
            bk0 = *(const bf16x8*)(kb + (size_t)(kc + 1) * 8192);
            bk1 = *(const bf16x8*)(kb + (size_t)(kc + 1) * 8192 + 4096);
        }
        // ---- P = 2^S -> f16 -> LDS in A-frag order (b64)
        {
            f16x4 ph;
#pragma unroll
            for (int r = 0; r < 4; ++r)
                ph[r] = (_Float16)__builtin_amdgcn_exp2f(sacc[r]);
            *(f16x4*)&lds.Pf[buf][pspan][pidx] = ph;
        }
        // ---- raw barrier: order LDS P only; do NOT drain vmcnt
        asm volatile("s_waitcnt lgkmcnt(0)" ::: "memory");
        __builtin_amdgcn_s_barrier();
        // ---- P A-frags: stride-1 b128 reads
        f16x8 ap[2];
#pragma unroll
        for (int sp = 0; sp < 2; ++sp)
            ap[sp] = *(const f16x8*)&lds.Pf[buf][sp][lane * 8];
        // ---- U += P @ V_group(w) (16x16x32 f16); L += P @ ones
        __builtin_amdgcn_s_setprio(1);
#pragma unroll
        for (int sp = 0; sp < 2; ++sp) {
            Uacc[0] = __builtin_amdgcn_mfma_f32_16x16x32_f16(ap[sp], vf[sp * 4 + 0], Uacc[0], 0, 0, 0);
            Uacc[1] = __builtin_amdgcn_mfma_f32_16x16x32_f16(ap[sp], vf[sp * 4 + 1], Uacc[1], 0, 0, 0);
            Uacc[2] = __builtin_amdgcn_mfma_f32_16x16x32_f16(ap[sp], vf[sp * 4 + 2], Uacc[2], 0, 0, 0);
            Uacc[3] = __builtin_amdgcn_mfma_f32_16x16x32_f16(ap[sp], vf[sp * 4 + 3], Uacc[3], 0, 0, 0);
            Lacc    = __builtin_amdgcn_mfma_f32_16x16x32_f16(ap[sp], kOnes, Lacc, 0, 0, 0);
        }
        __builtin_amdgcn_s_setprio(0);
        // dbuf: next iter writes the other buffer; its barrier orders WAR
    }

    __syncthreads();   // all P reads done; reuse LDS as bf16 U
#pragma unroll
    for (int dt = 0; dt < 4; ++dt)
#pragma unroll
        for (int r = 0; r < 4; ++r)
            lds.Ub[hi * 4 + r][w * 64 + dt * 16 + c] =
                (unsigned short)f2bf(Uacc[dt][r]);
    if (w == 0 && c == 0) {
#pragma unroll
        for (int r = 0; r < 4; ++r)
            Llds[hi * 4 + r] = Lacc[r];
    }
    __syncthreads();

    const float* wsf = (const float*)wsb;
    const float* nsq = wsf + (size_t)bh * 16;
    const float* vsw = wsf + 512 + (size_t)bh * 256;
    const int dd = t & 63, rq = t >> 6;
    float sg[4][4], ssum[4], omp[4], ov[4];
    const float inv22 = 1.0f / nsq[10];   // nsq[c0=2][c1=2]
#pragma unroll
    for (int gi = 0; gi < 4; ++gi) {
        float ss = 0.f, os = 0.f, ovv = 0.f;
#pragma unroll
        for (int gj = 0; gj < 4; ++gj) {
            float sgv = sqrtf(nsq[gi * 4 + gj] * inv22);
            sg[gi][gj] = sgv;
            ss += sgv;
            float om = fmaxf(1.0f - sgv, 0.0f);
            os += om;
            ovv += om * vsw[gj * 64 + dd];
        }
        ssum[gi] = ss; omp[gi] = os * 1024.0f; ov[gi] = ovv;
    }
    const size_t base = (size_t)bh * SEQ * DIM;
    float* attn_out = out + base;
    float* lse_out = out + (size_t)BH_TOT * SEQ * DIM + (size_t)bh * SEQ;
    for (int k = 0; k < 4; ++k) {
        const int r = k * 4 + rq;
        const float u0 = bf2f(lds.Ub[r][dd]);
        const float u1 = bf2f(lds.Ub[r][64 + dd]);
        const float u2 = bf2f(lds.Ub[r][128 + dd]);
        const float u3 = bf2f(lds.Ub[r][192 + dd]);
        const float Lr = Llds[r];
        const int orow = qt16 * 16 + r;
#pragma unroll
        for (int gi = 0; gi < 4; ++gi) {
            float num = ov[gi] + sg[gi][0] * u0 + sg[gi][1] * u1 + sg[gi][2] * u2 + sg[gi][3] * u3;
            float den = omp[gi] + ssum[gi] * Lr;
            attn_out[(size_t)(gi * 1024 + orow) * 64 + dd] = num * __builtin_amdgcn_rcpf(den);
            if (dd == gi) lse_out[gi * 1024 + orow] = __logf(den);
        }
    }
}

// ---------------- fallback path (small ws): R2 kernels ---------------------
__global__ __launch_bounds__(256) void prep_norm2(
    const float* __restrict__ query, const float* __restrict__ key,
    float* __restrict__ ws)
{
    __shared__ float ksm[4][64];
    __shared__ float wsum[4][16];
    const int t = threadIdx.x;
    const int bh = blockIdx.x >> 2, gi = blockIdx.x & 3;
    if (t < 64) ws[512 + blockIdx.x * 64 + t] = 0.f;
    ksm[t >> 6][t & 63] = key[((size_t)bh * SEQ + (size_t)(t >> 6) * PQ) * DIM + (t & 63)];
    __syncthreads();
    const int wv = t >> 6, lane = t & 63, c = lane & 15, hi = lane >> 4;
    bf16x8 bb0, bb1;
#pragma unroll
    for (int j = 0; j < 8; ++j) {
        bb0[j] = (c < 4) ? f2bf(ksm[c][hi * 8 + j]) : (short)0;
        bb1[j] = (c < 4) ? f2bf(ksm[c][32 + hi * 8 + j]) : (short)0;
    }
    float acc0 = 0.f, acc1 = 0.f, acc2 = 0.f, acc3 = 0.f;
    const float* qbase = query + ((size_t)bh * SEQ + (size_t)gi * PQ) * DIM;
    for (int it = 0; it < 16; ++it) {
        const int row = (wv * 16 + it) * 16 + c;
        const float* qp = qbase + (size_t)row * 64 + hi * 8;
        float4 a0 = *(const float4*)qp;
        float4 a1 = *(const float4*)(qp + 4);
        float4 a2 = *(const float4*)(qp + 32);
        float4 a3 = *(const float4*)(qp + 36);
        bf16x8 qa0, qa1;
        qa0[0] = f2bf(a0.x); qa0[1] = f2bf(a0.y); qa0[2] = f2bf(a0.z); qa0[3] = f2bf(a0.w);
        qa0[4] = f2bf(a1.x); qa0[5] = f2bf(a1.y); qa0[6] = f2bf(a1.z); qa0[7] = f2bf(a1.w);
        qa1[0] = f2bf(a2.x); qa1[1] = f2bf(a2.y); qa1[2] = f2bf(a2.z); qa1[3] = f2bf(a2.w);
        qa1[4] = f2bf(a3.x); qa1[5] = f2bf(a3.y); qa1[6] = f2bf(a3.z); qa1[7] = f2bf(a3.w);
        f32x4 s = (f32x4){0.f, 0.f, 0.f, 0.f};
        s = __builtin_amdgcn_mfma_f32_16x16x32_bf16(qa0, bb0, s, 0, 0, 0);
        s = __builtin_amdgcn_mfma_f32_16x16x32_bf16(qa1, bb1, s, 0, 0, 0);
        acc0 += s[0] * s[0]; acc1 += s[1] * s[1];
        acc2 += s[2] * s[2]; acc3 += s[3] * s[3];
    }
    float asum = acc0 + acc1 + acc2 + acc3;
    asum += __shfl_xor(asum, 16);
    asum += __shfl_xor(asum, 32);
    if (lane < 16) wsum[wv][lane] = asum;
    __syncthreads();
    if (t < 4) ws[bh * 16 + gi * 4 + t] = wsum[0][t] + wsum[1][t] + wsum[2][t] + wsum[3][t];
}

__global__ __launch_bounds__(256) void prep_vsum(
    const float* __restrict__ value, float* __restrict__ ws)
{
    __shared__ float part[16][16][4];
    const int t = threadIdx.x;
    const int bh = blockIdx.x >> 2, gj = blockIdx.x & 3;
    const float4* vv = (const float4*)(value + ((size_t)bh * SEQ + (size_t)gj * PQ) * DIM);
    const int c4 = t & 15, rg = t >> 4;
    float a0 = 0.f, a1 = 0.f, a2 = 0.f, a3 = 0.f;
    for (int r = rg; r < 1024; r += 16) {
        float4 x = vv[r * 16 + c4];
        a0 += x.x; a1 += x.y; a2 += x.z; a3 += x.w;
    }
    part[rg][c4][0] = a0; part[rg][c4][1] = a1;
    part[rg][c4][2] = a2; part[rg][c4][3] = a3;
    __syncthreads();
    if (t < 64) {
        const int cc = t >> 2, comp = t & 3;
        float s = 0.f;
#pragma unroll
        for (int g = 0; g < 16; ++g) s += part[g][cc][comp];
        ws[512 + bh * 256 + gj * 64 + cc * 4 + comp] = s;
    }
}

__global__ __launch_bounds__(256, 2) void kattn_fallback(
    const float* __restrict__ query, const float* __restrict__ key,
    const float* __restrict__ value, const float* __restrict__ ws,
    float* __restrict__ out)
{
    __shared__ union {
        struct { short Q[64][72]; short K[64][72]; short P[64][72]; } s;
        unsigned short U[64][264];
    } lds;
    __shared__ float Llds[64];
    const int blk = blockIdx.x;
    const int bh = blk >> 4, qt = blk & 15;
    const int t = threadIdx.x;
    const int w = t >> 6, lane = t & 63;
    const int c = lane & 15, hi = lane >> 4;
    const size_t base = (size_t)bh * SEQ * DIM;
    {
        const float* qp = query + base + (size_t)(2048 + qt * 64) * DIM;
#pragma unroll
        for (int k2 = 0; k2 < 4; ++k2) {
            int u = t + k2 * 256;
            int row = u >> 4, ci = (u & 15) * 4;
            float4 qv = *(const float4*)(qp + row * 64 + ci);
            bf16x4 h;
            h[0] = f2bf(qv.x); h[1] = f2bf(qv.y); h[2] = f2bf(qv.z); h[3] = f2bf(qv.w);
            *(bf16x4*)&lds.s.Q[row][ci] = h;
        }
    }
    __syncthreads();
    bf16x8 aq0 = *(const bf16x8*)&lds.s.Q[w * 16 + c][hi * 8];
    bf16x8 aq1 = *(const bf16x8*)&lds.s.Q[w * 16 + c][32 + hi * 8];
    f32x4 Uacc[4][4];
#pragma unroll
    for (int mt = 0; mt < 4; ++mt)
#pragma unroll
        for (int nt = 0; nt < 4; ++nt)
            Uacc[mt][nt] = (f32x4){0.f, 0.f, 0.f, 0.f};
    float Lacc[4] = {0.f, 0.f, 0.f, 0.f};
    const float* kp = key + base + (size_t)2048 * DIM;
    const float* vgrp = value + base + (size_t)w * PQ * DIM;
    for (int kc = 0; kc < 16; ++kc) {
        {
            const float* kcp = kp + (size_t)kc * 64 * DIM;
#pragma unroll
            for (int k2 = 0; k2 < 4; ++k2) {
                int u = t + k2 * 256;
                int row = u >> 4, ci = (u & 15) * 4;
                float4 kv = *(const float4*)(kcp + row * 64 + ci);
                bf16x4 h;
                h[0] = f2bf(kv.x); h[1] = f2bf(kv.y); h[2] = f2bf(kv.z); h[3] = f2bf(kv.w);
                *(bf16x4*)&lds.s.K[row][ci] = h;
            }
        }
        __syncthreads();
        f32x4 sacc[4];
#pragma unroll
        for (int nt = 0; nt < 4; ++nt) sacc[nt] = (f32x4){0.f, 0.f, 0.f, 0.f};
#pragma unroll
        for (int nt = 0; nt < 4; ++nt) {
            bf16x8 bk = *(const bf16x8*)&lds.s.K[nt * 16 + c][hi * 8];
            sacc[nt] = __builtin_amdgcn_mfma_f32_16x16x32_bf16(aq0, bk, sacc[nt], 0, 0, 0);
        }
#pragma unroll
        for (int nt = 0; nt < 4; ++nt) {
            bf16x8 bk = *(const bf16x8*)&lds.s.K[nt * 16 + c][32 + hi * 8];
            sacc[nt] = __builtin_amdgcn_mfma_f32_16x16x32_bf16(aq1, bk, sacc[nt], 0, 0, 0);
        }
        float p[4][4];
#pragma unroll
        for (int nt = 0; nt < 4; ++nt)
#pragma unroll
            for (int r = 0; r < 4; ++r)
                p[nt][r] = __expf(sacc[nt][r] * 0.125f);
#pragma unroll
        for (int r = 0; r < 4; ++r) {
            float rs = p[0][r] + p[1][r] + p[2][r] + p[3][r];
            rs += __shfl_xor(rs, 1); rs += __shfl_xor(rs, 2);
            rs += __shfl_xor(rs, 4); rs += __shfl_xor(rs, 8);
            Lacc[r] += rs;
        }
#pragma unroll
        for (int nt = 0; nt < 4; ++nt)
#pragma unroll
            for (int r = 0; r < 4; ++r)
                lds.s.P[w * 16 + hi * 4 + r][nt * 16 + c] = (unsigned short)f2bf(p[nt][r]);
        __syncthreads();
        bf16x8 ap2[4][2];
#pragma unroll
        for (int mt = 0; mt < 4; ++mt) {
            ap2[mt][0] = *(const bf16x8*)&lds.s.P[mt * 16 + c][hi * 8];
            ap2[mt][1] = *(const bf16x8*)&lds.s.P[mt * 16 + c][32 + hi * 8];
        }
        const float* vp = vgrp + (size_t)kc * 64 * DIM;
#pragma unroll
        for (int kt = 0; kt < 2; ++kt) {
#pragma unroll
            for (int nt = 0; nt < 4; ++nt) {
                const float* vpp = vp + (kt * 32 + hi * 8) * 64 + nt * 16 + c;
                bf16x8 bv;
#pragma unroll
                for (int j = 0; j < 8; ++j) bv[j] = f2bf(vpp[j * 64]);
#pragma unroll
                for (int mt = 0; mt < 4; ++mt)
                    Uacc[mt][nt] = __builtin_amdgcn_mfma_f32_16x16x32_bf16(ap2[mt][kt], bv, Uacc[mt][nt], 0, 0, 0);
            }
        }
        __syncthreads();
    }
#pragma unroll
    for (int mt = 0; mt < 4; ++mt)
#pragma unroll
        for (int nt = 0; nt < 4; ++nt)
#pragma unroll
            for (int r = 0; r < 4; ++r)
                lds.U[mt * 16 + hi * 4 + r][w * 64 + nt * 16 + c] =
                    (unsigned short)f2bf(Uacc[mt][nt][r]);
    if (c == 0) {
#pragma unroll
        for (int r = 0; r < 4; ++r) Llds[w * 16 + hi * 4 + r] = Lacc[r];
    }
    __syncthreads();
    const float* nsq = ws + bh * 16;
    const float* vsw = ws + 512 + bh * 256;
    const int dd = t & 63, rq = t >> 6;
    float sg[4][4], ssum[4], omp[4], ov[4];
    const float inv22 = 1.0f / nsq[10];
#pragma unroll
    for (int gi = 0; gi < 4; ++gi) {
        float ss = 0.f, os = 0.f, ovv = 0.f;
#pragma unroll
        for (int gj = 0; gj < 4; ++gj) {
            float sgv = sqrtf(nsq[gi * 4 + gj] * inv22);
            sg[gi][gj] = sgv;
            ss += sgv;
            float om = fmaxf(1.0f - sgv, 0.0f);
            os += om;
            ovv += om * vsw[gj * 64 + dd];
        }
        ssum[gi] = ss; omp[gi] = os * 1024.0f; ov[gi] = ovv;
    }
    float* attn_out = out + base;
    float* lse_out = out + (size_t)BH_TOT * SEQ * DIM + (size_t)bh * SEQ;
    for (int k = 0; k < 16; ++k) {
        const int r = k * 4 + rq;
        const float u0 = bf2f(lds.U[r][dd]);
        const float u1 = bf2f(lds.U[r][64 + dd]);
        const float u2 = bf2f(lds.U[r][128 + dd]);
        const float u3 = bf2f(lds.U[r][192 + dd]);
        const float Lr = Llds[r];
        const int orow = qt * 64 + r;
#pragma unroll
        for (int gi = 0; gi < 4; ++gi) {
            float num = ov[gi] + sg[gi][0] * u0 + sg[gi][1] * u1 + sg[gi][2] * u2 + sg[gi][3] * u3;
            float den = omp[gi] + ssum[gi] * Lr;
            attn_out[(size_t)(gi * 1024 + orow) * 64 + dd] = num / den;
            if (dd == gi) lse_out[gi * 1024 + orow] = __logf(den);
        }
    }
}

extern "C" void kernel_launch(void* const* d_in, const int* in_sizes, int n_in,
                              void* d_out, int out_size, void* d_ws, size_t ws_size,
                              hipStream_t stream)
{
    (void)in_sizes; (void)n_in; (void)out_size;
    const float* query = (const float*)d_in[0];
    const float* key   = (const float*)d_in[1];
    const float* value = (const float*)d_in[2];
    float* ws   = (float*)d_ws;
    char*  wsb  = (char*)d_ws;
    float* outp = (float*)d_out;

    if (ws_size >= WS_NEED) {
        (void)hipMemsetAsync(d_ws, 0, QB_OFF, stream);   // zero nsq + vsum
        mega_prep<<<3584, 256, 0, stream>>>(query, key, value, ws, wsb);
        kattn4<<<2048, 256, 0, stream>>>(wsb, outp);
    } else {
        prep_norm2<<<128, 256, 0, stream>>>(query, key, ws);
        prep_vsum<<<128, 256, 0, stream>>>(value, ws);
        kattn_fallback<<<512, 256, 0, stream>>>(query, key, value, ws, outp);
    }
}

// Round 11
// 169.120 us; speedup vs baseline: 1.0848x; 1.0848x over previous
//
#include <hip/hip_runtime.h>
#include <hip/hip_bf16.h>

// KroneckerAttention on MI355X — FINAL (R9 configuration, best measured).
// B=2,H=16 (BH=32), NQ=NK=4096, D=64, m=n=4, pq=pk=1024, c0=c1=2, scale=1/8.
//
// ws layout:
//   floats [0,512)    : nsq[bh][gi][gj]    (atomicAdd partials, memset to 0)
//   floats [512,8704) : vsum[bh][gj][dd]   (atomicAdd partials, memset to 0)
//   bytes  [34816, +4MB)  : Qb  bf16 16x16x32 B-frags, pre-scaled 0.125*log2e
//   bytes  [+4MB, +8MB)   : Kb  bf16 16x16x32 A-frags (central key group)
//   bytes  [+8MB, +24MB)  : Vb  f16  16x16x32 B-frags (all value rows)
//
// Session findings (10 rounds): kattn4's 16x64 4-wave structure is invariant
// at ~42-43us under barrier semantics, V-traffic, pipeline skew, exchange
// elimination, iteration count, and occupancy changes — latency floor for
// this structure. Bank conflicts were cosmetic (7M->0.5M, no perf change,
// mostly the old fp32 epilogue). launch_bounds 2nd arg CAPS the register
// allocator (R8: (256,8) -> 32 VGPR -> spills -> 414us); keep (256,4).
// Smaller q-tiles regress: per-iteration overhead (V/K loads, exp, barrier)
// stops amortizing (R10: 16-q -> 59us despite higher occupancy).

#define BH_TOT 32
#define SEQ    4096
#define DIM    64
#define PQ     1024

#define QB_OFF 34816u
#define KB_OFF (QB_OFF + 4u*1024u*1024u)
#define VB_OFF (KB_OFF + 4u*1024u*1024u)
#define WS_NEED (VB_OFF + 16u*1024u*1024u)

#define QSCALE 0.1803368801111204f   // 0.125 * log2(e)

typedef __attribute__((ext_vector_type(8))) short bf16x8;
typedef __attribute__((ext_vector_type(4))) short bf16x4;
typedef __attribute__((ext_vector_type(4))) float f32x4;
typedef __attribute__((ext_vector_type(4))) _Float16 f16x4;
typedef __attribute__((ext_vector_type(8))) _Float16 f16x8;

__device__ __forceinline__ short f2bf(float x) {
    unsigned u = __float_as_uint(x);
    u = u + 0x7fffu + ((u >> 16) & 1u);   // RNE truncate to bf16
    return (short)(u >> 16);
}
__device__ __forceinline__ float bf2f(unsigned short h) {
    return __uint_as_float(((unsigned)h) << 16);
}

// ---------------- mega_prep: grid 3584 -------------------------------------
// [0,512)     : norm partials (bh,gi,chunk of 256 q rows) -> atomicAdd nsq
// [512,2560)  : V f16 frags + vsum atomic partials (bh,gj,kc)
// [2560,3072) : Q bf16 frags (pre-scaled)
// [3072,3584) : K bf16 frags (central group)
__global__ __launch_bounds__(256) void mega_prep(
    const float* __restrict__ query, const float* __restrict__ key,
    const float* __restrict__ value, float* __restrict__ ws,
    char* __restrict__ wsb)
{
    __shared__ union {
        struct { float ksm[4][64]; float wsum[4][16]; } n;
        struct { float Ls[64][68]; float ps[4][64]; } v;
    } sm;
    const int t = threadIdx.x;
    const int bid = blockIdx.x;

    if (bid < 512) {
        // ---- norm: w = Q @ k_sample^T, nsq[gi][gj] += sum_q w^2 (256 rows)
        const int bh = bid >> 4, gi = (bid >> 2) & 3, chunk = bid & 3;
        sm.n.ksm[t >> 6][t & 63] =
            key[((size_t)bh * SEQ + (size_t)(t >> 6) * PQ) * DIM + (t & 63)];
        __syncthreads();
        const int wv = t >> 6, lane = t & 63, c = lane & 15, hi = lane >> 4;
        bf16x8 bb0, bb1;
#pragma unroll
        for (int j = 0; j < 8; ++j) {
            bb0[j] = (c < 4) ? f2bf(sm.n.ksm[c][hi * 8 + j]) : (short)0;
            bb1[j] = (c < 4) ? f2bf(sm.n.ksm[c][32 + hi * 8 + j]) : (short)0;
        }
        float acc0 = 0.f, acc1 = 0.f, acc2 = 0.f, acc3 = 0.f;
        const float* qbase = query +
            ((size_t)bh * SEQ + (size_t)gi * PQ + (size_t)chunk * 256) * DIM;
#pragma unroll
        for (int it = 0; it < 4; ++it) {
            const int row = (wv * 4 + it) * 16 + c;
            const float* qp = qbase + (size_t)row * 64 + hi * 8;
            float4 a0 = *(const float4*)qp;
            float4 a1 = *(const float4*)(qp + 4);
            float4 a2 = *(const float4*)(qp + 32);
            float4 a3 = *(const float4*)(qp + 36);
            bf16x8 qa0, qa1;
            qa0[0] = f2bf(a0.x); qa0[1] = f2bf(a0.y); qa0[2] = f2bf(a0.z); qa0[3] = f2bf(a0.w);
            qa0[4] = f2bf(a1.x); qa0[5] = f2bf(a1.y); qa0[6] = f2bf(a1.z); qa0[7] = f2bf(a1.w);
            qa1[0] = f2bf(a2.x); qa1[1] = f2bf(a2.y); qa1[2] = f2bf(a2.z); qa1[3] = f2bf(a2.w);
            qa1[4] = f2bf(a3.x); qa1[5] = f2bf(a3.y); qa1[6] = f2bf(a3.z); qa1[7] = f2bf(a3.w);
            f32x4 s = (f32x4){0.f, 0.f, 0.f, 0.f};
            s = __builtin_amdgcn_mfma_f32_16x16x32_bf16(qa0, bb0, s, 0, 0, 0);
            s = __builtin_amdgcn_mfma_f32_16x16x32_bf16(qa1, bb1, s, 0, 0, 0);
            acc0 += s[0] * s[0]; acc1 += s[1] * s[1];
            acc2 += s[2] * s[2]; acc3 += s[3] * s[3];
        }
        float asum = acc0 + acc1 + acc2 + acc3;
        asum += __shfl_xor(asum, 16);
        asum += __shfl_xor(asum, 32);
        if (lane < 16) sm.n.wsum[wv][lane] = asum;
        __syncthreads();
        if (t < 4)
            atomicAdd(&ws[bh * 16 + gi * 4 + t],
                      sm.n.wsum[0][t] + sm.n.wsum[1][t] + sm.n.wsum[2][t] + sm.n.wsum[3][t]);
    } else if (bid < 2560) {
        // ---- conv_v: (bh,gj,kc) -> f16 B-frags + vsum atomic partial
        const int blk = bid - 512;
        const int bh = blk >> 6, gj = (blk >> 4) & 3, kc = blk & 15;
        const float* src = value + ((size_t)bh * SEQ + gj * PQ + kc * 64) * DIM;
#pragma unroll
        for (int i = 0; i < 4; ++i) {
            const int u = t + i * 256;
            const int row = u >> 4, c4 = (u & 15) * 4;
            *(float4*)&sm.v.Ls[row][c4] = *(const float4*)(src + row * 64 + c4);
        }
        __syncthreads();
        {
            const int d = t & 63, rg = t >> 6;
            float s = 0.f;
#pragma unroll
            for (int i = 0; i < 16; ++i) s += sm.v.Ls[rg * 16 + i][d];
            sm.v.ps[rg][d] = s;
        }
        __syncthreads();
        if (t < 64) {
            float tot = sm.v.ps[0][t] + sm.v.ps[1][t] + sm.v.ps[2][t] + sm.v.ps[3][t];
            atomicAdd(&ws[512 + bh * 256 + gj * 64 + t], tot);
        }
        // 16x16x32 f16 B-frags: lane(c,hi) holds V[span*32 + hi*8 + j][dt*16 + c]
#pragma unroll
        for (int i = 0; i < 2; ++i) {
            const int sid = t + i * 256;
            const int pl = sid >> 8, dt = (sid >> 6) & 3, lane = sid & 63;
            const int c = lane & 15, hi = lane >> 4;
            f16x8 h;
#pragma unroll
            for (int j = 0; j < 8; ++j)
                h[j] = (_Float16)sm.v.Ls[pl * 32 + hi * 8 + j][dt * 16 + c];
            const size_t off = ((((size_t)(bh * 4 + gj) * 32 + kc * 2 + pl) * 4 + dt) * 64 + lane) * 16;
            *(f16x8*)(wsb + VB_OFF + off) = h;
        }
    } else if (bid < 3072) {
        // ---- Q frags (pre-scaled by 0.125*log2e)
        const int qb = bid - 2560;
        const int bh = qb >> 4, qt = qb & 15;
#pragma unroll
        for (int i = 0; i < 2; ++i) {
            const int sid = t + i * 256;
            const int mt = sid >> 7, kh = (sid >> 6) & 1, lane = sid & 63;
            const int c = lane & 15, hi = lane >> 4;
            const float* p = query + ((size_t)bh * SEQ + 2048 + qt * 64 + mt * 16 + c) * DIM
                             + kh * 32 + hi * 8;
            float4 a = *(const float4*)p, b = *(const float4*)(p + 4);
            bf16x8 h;
            h[0] = f2bf(a.x * QSCALE); h[1] = f2bf(a.y * QSCALE);
            h[2] = f2bf(a.z * QSCALE); h[3] = f2bf(a.w * QSCALE);
            h[4] = f2bf(b.x * QSCALE); h[5] = f2bf(b.y * QSCALE);
            h[6] = f2bf(b.z * QSCALE); h[7] = f2bf(b.w * QSCALE);
            const size_t fidx = ((size_t)(bh * 16 + qt) * 4 + mt) * 2 + kh;
            *(bf16x8*)(wsb + QB_OFF + fidx * 1024 + lane * 16) = h;
        }
    } else {
        // ---- K frags (central group)
        const int b2 = bid - 3072;
        const int bh = b2 >> 4, kc = b2 & 15;
#pragma unroll
        for (int i = 0; i < 2; ++i) {
            const int sid = t + i * 256;
            const int kh = sid >> 8, nt = (sid >> 6) & 3, lane = sid & 63;
            const int c = lane & 15, hi = lane >> 4;
            const float* p = key + ((size_t)bh * SEQ + 2048 + kc * 64 + nt * 16 + c) * DIM
                             + kh * 32 + hi * 8;
            float4 a = *(const float4*)p, b = *(const float4*)(p + 4);
            bf16x8 h;
            h[0] = f2bf(a.x); h[1] = f2bf(a.y); h[2] = f2bf(a.z); h[3] = f2bf(a.w);
            h[4] = f2bf(b.x); h[5] = f2bf(b.y); h[6] = f2bf(b.z); h[7] = f2bf(b.w);
            const size_t fidx = ((size_t)(bh * 16 + kc) * 2 + kh) * 4 + nt;
            *(bf16x8*)(wsb + KB_OFF + fidx * 1024 + lane * 16) = h;
        }
    }
}

// ---------------- kattn4: R3 loop + bf16-U epilogue (R9, best) -------------
// grid = 1024, block = 256 (4 waves), XCD-swizzled.
__global__ __launch_bounds__(256, 4) void kattn4(
    const char* __restrict__ wsb, float* __restrict__ out)
{
    __shared__ union {
        _Float16 Pf[2][2][2][512];     // [buf][mt][span][frag] — 8 KB
        unsigned short Ub[32][260];    // epilogue: bf16 U — 16.6 KB
    } lds;
    __shared__ float Llds[32];

    const int blk = blockIdx.x;
    const int slot = blk >> 3;
    const int bh = (blk & 7) * 4 + (slot >> 5);   // XCD-major
    const int qt = slot & 31;
    const int t = threadIdx.x;
    const int w = t >> 6, lane = t & 63;
    const int c = lane & 15, hi = lane >> 4;

    // Q B-frags (pre-scaled): strips s = qt*2 + qt2
    bf16x8 aq[2][2];
#pragma unroll
    for (int qt2 = 0; qt2 < 2; ++qt2) {
        const int s = qt * 2 + qt2;
        const size_t fr = ((size_t)(bh * 16 + (s >> 2)) * 4 + (s & 3)) * 2;
        aq[qt2][0] = *(const bf16x8*)(wsb + QB_OFF + fr * 1024 + lane * 16);
        aq[qt2][1] = *(const bf16x8*)(wsb + QB_OFF + (fr + 1) * 1024 + lane * 16);
    }
    const char* kb = wsb + KB_OFF + ((size_t)(bh * 16) * 8) * 1024 + (size_t)w * 1024 + lane * 16;
    const char* vb = wsb + VB_OFF + ((size_t)(bh * 4 + w) * 128) * 1024 + lane * 16;

    f32x4 Uacc[2][4];
#pragma unroll
    for (int mt = 0; mt < 2; ++mt)
#pragma unroll
        for (int dt = 0; dt < 4; ++dt)
            Uacc[mt][dt] = (f32x4){0.f, 0.f, 0.f, 0.f};
    f32x4 Lacc[2];
    Lacc[0] = (f32x4){0.f, 0.f, 0.f, 0.f};
    Lacc[1] = (f32x4){0.f, 0.f, 0.f, 0.f};
    f16x8 kOnes;
#pragma unroll
    for (int j = 0; j < 8; ++j) kOnes[j] = (_Float16)1.f;

    // P write coords (A-frag order): element (m=c, k=w*16+hi*4+r)
    const int k0 = w * 16 + hi * 4;
    const int pspan = k0 >> 5;                    // w>>1
    const int pidx = (c + 16 * ((k0 & 31) >> 3)) * 8 + (k0 & 7);  // b64 dest

    bf16x8 bk0 = *(const bf16x8*)(kb);
    bf16x8 bk1 = *(const bf16x8*)(kb + 4096);

    for (int kc = 0; kc < 16; ++kc) {
        const int buf = kc & 1;
        // ---- V(kc) loads first: consumed after the barrier, so S-MFMA +
        // exp2/pack + barrier cover their L2 latency.
        const char* vcb = vb + (size_t)kc * 8192;
        f16x8 vf[8];
#pragma unroll
        for (int u = 0; u < 8; ++u) vf[u] = *(const f16x8*)(vcb + u * 1024);
        // ---- S^T strip: A = this wave's 16 keys, B = 32 q (2 tiles)
        f32x4 sacc[2];
        __builtin_amdgcn_s_setprio(1);
#pragma unroll
        for (int qt2 = 0; qt2 < 2; ++qt2) {
            f32x4 s = (f32x4){0.f, 0.f, 0.f, 0.f};
            s = __builtin_amdgcn_mfma_f32_16x16x32_bf16(bk0, aq[qt2][0], s, 0, 0, 0);
            s = __builtin_amdgcn_mfma_f32_16x16x32_bf16(bk1, aq[qt2][1], s, 0, 0, 0);
            sacc[qt2] = s;
        }
        __builtin_amdgcn_s_setprio(0);
        // ---- prefetch K(kc+1); stays in flight across the barrier (counted)
        if (kc < 15) {
            bk0 = *(const bf16x8*)(kb + (size_t)(kc + 1) * 8192);
            bk1 = *(const bf16x8*)(kb + (size_t)(kc + 1) * 8192 + 4096);
        }
        // ---- P = 2^S -> f16 -> LDS in A-frag order (b64, <=2-way banks)
#pragma unroll
        for (int qt2 = 0; qt2 < 2; ++qt2) {
            f16x4 ph;
#pragma unroll
            for (int r = 0; r < 4; ++r)
                ph[r] = (_Float16)__builtin_amdgcn_exp2f(sacc[qt2][r]);
            *(f16x4*)&lds.Pf[buf][qt2][pspan][pidx] = ph;
        }
        // ---- raw barrier: order LDS P only; do NOT drain vmcnt
        asm volatile("s_waitcnt lgkmcnt(0)" ::: "memory");
        __builtin_amdgcn_s_barrier();
        // ---- P A-frags: stride-1 b128 reads (conflict-free)
        f16x8 ap[2][2];
#pragma unroll
        for (int mt = 0; mt < 2; ++mt)
#pragma unroll
            for (int sp = 0; sp < 2; ++sp)
                ap[mt][sp] = *(const f16x8*)&lds.Pf[buf][mt][sp][lane * 8];
        // ---- U += P @ V_group(w) (16x16x32 f16); L += P @ ones
        __builtin_amdgcn_s_setprio(1);
#pragma unroll
        for (int mt = 0; mt < 2; ++mt) {
#pragma unroll
            for (int sp = 0; sp < 2; ++sp) {
                Uacc[mt][0] = __builtin_amdgcn_mfma_f32_16x16x32_f16(ap[mt][sp], vf[sp * 4 + 0], Uacc[mt][0], 0, 0, 0);
                Uacc[mt][1] = __builtin_amdgcn_mfma_f32_16x16x32_f16(ap[mt][sp], vf[sp * 4 + 1], Uacc[mt][1], 0, 0, 0);
                Uacc[mt][2] = __builtin_amdgcn_mfma_f32_16x16x32_f16(ap[mt][sp], vf[sp * 4 + 2], Uacc[mt][2], 0, 0, 0);
                Uacc[mt][3] = __builtin_amdgcn_mfma_f32_16x16x32_f16(ap[mt][sp], vf[sp * 4 + 3], Uacc[mt][3], 0, 0, 0);
                Lacc[mt]    = __builtin_amdgcn_mfma_f32_16x16x32_f16(ap[mt][sp], kOnes, Lacc[mt], 0, 0, 0);
            }
        }
        __builtin_amdgcn_s_setprio(0);
        // dbuf: next iter writes the other buffer; its barrier orders WAR
    }

    __syncthreads();   // all P reads done; reuse LDS as bf16 U
#pragma unroll
    for (int mt = 0; mt < 2; ++mt)
#pragma unroll
        for (int dt = 0; dt < 4; ++dt)
#pragma unroll
            for (int r = 0; r < 4; ++r)
                lds.Ub[mt * 16 + hi * 4 + r][w * 64 + dt * 16 + c] =
                    (unsigned short)f2bf(Uacc[mt][dt][r]);
    if (w == 0 && c == 0) {
#pragma unroll
        for (int mt = 0; mt < 2; ++mt)
#pragma unroll
            for (int r = 0; r < 4; ++r)
                Llds[mt * 16 + hi * 4 + r] = Lacc[mt][r];
    }
    __syncthreads();

    const float* wsf = (const float*)wsb;
    const float* nsq = wsf + (size_t)bh * 16;
    const float* vsw = wsf + 512 + (size_t)bh * 256;
    const int dd = t & 63, rq = t >> 6;
    float sg[4][4], ssum[4], omp[4], ov[4];
    const float inv22 = 1.0f / nsq[10];   // nsq[c0=2][c1=2]
#pragma unroll
    for (int gi = 0; gi < 4; ++gi) {
        float ss = 0.f, os = 0.f, ovv = 0.f;
#pragma unroll
        for (int gj = 0; gj < 4; ++gj) {
            float sgv = sqrtf(nsq[gi * 4 + gj] * inv22);
            sg[gi][gj] = sgv;
            ss += sgv;
            float om = fmaxf(1.0f - sgv, 0.0f);
            os += om;
            ovv += om * vsw[gj * 64 + dd];
        }
        ssum[gi] = ss; omp[gi] = os * 1024.0f; ov[gi] = ovv;
    }
    const size_t base = (size_t)bh * SEQ * DIM;
    float* attn_out = out + base;
    float* lse_out = out + (size_t)BH_TOT * SEQ * DIM + (size_t)bh * SEQ;
    for (int k = 0; k < 8; ++k) {
        const int r = k * 4 + rq;
        const float u0 = bf2f(lds.Ub[r][dd]);
        const float u1 = bf2f(lds.Ub[r][64 + dd]);
        const float u2 = bf2f(lds.Ub[r][128 + dd]);
        const float u3 = bf2f(lds.Ub[r][192 + dd]);
        const float Lr = Llds[r];
        const int orow = qt * 32 + r;
#pragma unroll
        for (int gi = 0; gi < 4; ++gi) {
            float num = ov[gi] + sg[gi][0] * u0 + sg[gi][1] * u1 + sg[gi][2] * u2 + sg[gi][3] * u3;
            float den = omp[gi] + ssum[gi] * Lr;
            attn_out[(size_t)(gi * 1024 + orow) * 64 + dd] = num * __builtin_amdgcn_rcpf(den);
            if (dd == gi) lse_out[gi * 1024 + orow] = __logf(den);
        }
    }
}

// ---------------- fallback path (small ws): R2 kernels ---------------------
__global__ __launch_bounds__(256) void prep_norm2(
    const float* __restrict__ query, const float* __restrict__ key,
    float* __restrict__ ws)
{
    __shared__ float ksm[4][64];
    __shared__ float wsum[4][16];
    const int t = threadIdx.x;
    const int bh = blockIdx.x >> 2, gi = blockIdx.x & 3;
    if (t < 64) ws[512 + blockIdx.x * 64 + t] = 0.f;
    ksm[t >> 6][t & 63] = key[((size_t)bh * SEQ + (size_t)(t >> 6) * PQ) * DIM + (t & 63)];
    __syncthreads();
    const int wv = t >> 6, lane = t & 63, c = lane & 15, hi = lane >> 4;
    bf16x8 bb0, bb1;
#pragma unroll
    for (int j = 0; j < 8; ++j) {
        bb0[j] = (c < 4) ? f2bf(ksm[c][hi * 8 + j]) : (short)0;
        bb1[j] = (c < 4) ? f2bf(ksm[c][32 + hi * 8 + j]) : (short)0;
    }
    float acc0 = 0.f, acc1 = 0.f, acc2 = 0.f, acc3 = 0.f;
    const float* qbase = query + ((size_t)bh * SEQ + (size_t)gi * PQ) * DIM;
    for (int it = 0; it < 16; ++it) {
        const int row = (wv * 16 + it) * 16 + c;
        const float* qp = qbase + (size_t)row * 64 + hi * 8;
        float4 a0 = *(const float4*)qp;
        float4 a1 = *(const float4*)(qp + 4);
        float4 a2 = *(const float4*)(qp + 32);
        float4 a3 = *(const float4*)(qp + 36);
        bf16x8 qa0, qa1;
        qa0[0] = f2bf(a0.x); qa0[1] = f2bf(a0.y); qa0[2] = f2bf(a0.z); qa0[3] = f2bf(a0.w);
        qa0[4] = f2bf(a1.x); qa0[5] = f2bf(a1.y); qa0[6] = f2bf(a1.z); qa0[7] = f2bf(a1.w);
        qa1[0] = f2bf(a2.x); qa1[1] = f2bf(a2.y); qa1[2] = f2bf(a2.z); qa1[3] = f2bf(a2.w);
        qa1[4] = f2bf(a3.x); qa1[5] = f2bf(a3.y); qa1[6] = f2bf(a3.z); qa1[7] = f2bf(a3.w);
        f32x4 s = (f32x4){0.f, 0.f, 0.f, 0.f};
        s = __builtin_amdgcn_mfma_f32_16x16x32_bf16(qa0, bb0, s, 0, 0, 0);
        s = __builtin_amdgcn_mfma_f32_16x16x32_bf16(qa1, bb1, s, 0, 0, 0);
        acc0 += s[0] * s[0]; acc1 += s[1] * s[1];
        acc2 += s[2] * s[2]; acc3 += s[3] * s[3];
    }
    float asum = acc0 + acc1 + acc2 + acc3;
    asum += __shfl_xor(asum, 16);
    asum += __shfl_xor(asum, 32);
    if (lane < 16) wsum[wv][lane] = asum;
    __syncthreads();
    if (t < 4) ws[bh * 16 + gi * 4 + t] = wsum[0][t] + wsum[1][t] + wsum[2][t] + wsum[3][t];
}

__global__ __launch_bounds__(256) void prep_vsum(
    const float* __restrict__ value, float* __restrict__ ws)
{
    __shared__ float part[16][16][4];
    const int t = threadIdx.x;
    const int bh = blockIdx.x >> 2, gj = blockIdx.x & 3;
    const float4* vv = (const float4*)(value + ((size_t)bh * SEQ + (size_t)gj * PQ) * DIM);
    const int c4 = t & 15, rg = t >> 4;
    float a0 = 0.f, a1 = 0.f, a2 = 0.f, a3 = 0.f;
    for (int r = rg; r < 1024; r += 16) {
        float4 x = vv[r * 16 + c4];
        a0 += x.x; a1 += x.y; a2 += x.z; a3 += x.w;
    }
    part[rg][c4][0] = a0; part[rg][c4][1] = a1;
    part[rg][c4][2] = a2; part[rg][c4][3] = a3;
    __syncthreads();
    if (t < 64) {
        const int cc = t >> 2, comp = t & 3;
        float s = 0.f;
#pragma unroll
        for (int g = 0; g < 16; ++g) s += part[g][cc][comp];
        ws[512 + bh * 256 + gj * 64 + cc * 4 + comp] = s;
    }
}

__global__ __launch_bounds__(256, 2) void kattn_fallback(
    const float* __restrict__ query, const float* __restrict__ key,
    const float* __restrict__ value, const float* __restrict__ ws,
    float* __restrict__ out)
{
    __shared__ union {
        struct { short Q[64][72]; short K[64][72]; short P[64][72]; } s;
        unsigned short U[64][264];
    } lds;
    __shared__ float Llds[64];
    const int blk = blockIdx.x;
    const int bh = blk >> 4, qt = blk & 15;
    const int t = threadIdx.x;
    const int w = t >> 6, lane = t & 63;
    const int c = lane & 15, hi = lane >> 4;
    const size_t base = (size_t)bh * SEQ * DIM;
    {
        const float* qp = query + base + (size_t)(2048 + qt * 64) * DIM;
#pragma unroll
        for (int k2 = 0; k2 < 4; ++k2) {
            int u = t + k2 * 256;
            int row = u >> 4, ci = (u & 15) * 4;
            float4 qv = *(const float4*)(qp + row * 64 + ci);
            bf16x4 h;
            h[0] = f2bf(qv.x); h[1] = f2bf(qv.y); h[2] = f2bf(qv.z); h[3] = f2bf(qv.w);
            *(bf16x4*)&lds.s.Q[row][ci] = h;
        }
    }
    __syncthreads();
    bf16x8 aq0 = *(const bf16x8*)&lds.s.Q[w * 16 + c][hi * 8];
    bf16x8 aq1 = *(const bf16x8*)&lds.s.Q[w * 16 + c][32 + hi * 8];
    f32x4 Uacc[4][4];
#pragma unroll
    for (int mt = 0; mt < 4; ++mt)
#pragma unroll
        for (int nt = 0; nt < 4; ++nt)
            Uacc[mt][nt] = (f32x4){0.f, 0.f, 0.f, 0.f};
    float Lacc[4] = {0.f, 0.f, 0.f, 0.f};
    const float* kp = key + base + (size_t)2048 * DIM;
    const float* vgrp = value + base + (size_t)w * PQ * DIM;
    for (int kc = 0; kc < 16; ++kc) {
        {
            const float* kcp = kp + (size_t)kc * 64 * DIM;
#pragma unroll
            for (int k2 = 0; k2 < 4; ++k2) {
                int u = t + k2 * 256;
                int row = u >> 4, ci = (u & 15) * 4;
                float4 kv = *(const float4*)(kcp + row * 64 + ci);
                bf16x4 h;
                h[0] = f2bf(kv.x); h[1] = f2bf(kv.y); h[2] = f2bf(kv.z); h[3] = f2bf(kv.w);
                *(bf16x4*)&lds.s.K[row][ci] = h;
            }
        }
        __syncthreads();
        f32x4 sacc[4];
#pragma unroll
        for (int nt = 0; nt < 4; ++nt) sacc[nt] = (f32x4){0.f, 0.f, 0.f, 0.f};
#pragma unroll
        for (int nt = 0; nt < 4; ++nt) {
            bf16x8 bk = *(const bf16x8*)&lds.s.K[nt * 16 + c][hi * 8];
            sacc[nt] = __builtin_amdgcn_mfma_f32_16x16x32_bf16(aq0, bk, sacc[nt], 0, 0, 0);
        }
#pragma unroll
        for (int nt = 0; nt < 4; ++nt) {
            bf16x8 bk = *(const bf16x8*)&lds.s.K[nt * 16 + c][32 + hi * 8];
            sacc[nt] = __builtin_amdgcn_mfma_f32_16x16x32_bf16(aq1, bk, sacc[nt], 0, 0, 0);
        }
        float p[4][4];
#pragma unroll
        for (int nt = 0; nt < 4; ++nt)
#pragma unroll
            for (int r = 0; r < 4; ++r)
                p[nt][r] = __expf(sacc[nt][r] * 0.125f);
#pragma unroll
        for (int r = 0; r < 4; ++r) {
            float rs = p[0][r] + p[1][r] + p[2][r] + p[3][r];
            rs += __shfl_xor(rs, 1); rs += __shfl_xor(rs, 2);
            rs += __shfl_xor(rs, 4); rs += __shfl_xor(rs, 8);
            Lacc[r] += rs;
        }
#pragma unroll
        for (int nt = 0; nt < 4; ++nt)
#pragma unroll
            for (int r = 0; r < 4; ++r)
                lds.s.P[w * 16 + hi * 4 + r][nt * 16 + c] = (unsigned short)f2bf(p[nt][r]);
        __syncthreads();
        bf16x8 ap2[4][2];
#pragma unroll
        for (int mt = 0; mt < 4; ++mt) {
            ap2[mt][0] = *(const bf16x8*)&lds.s.P[mt * 16 + c][hi * 8];
            ap2[mt][1] = *(const bf16x8*)&lds.s.P[mt * 16 + c][32 + hi * 8];
        }
        const float* vp = vgrp + (size_t)kc * 64 * DIM;
#pragma unroll
        for (int kt = 0; kt < 2; ++kt) {
#pragma unroll
            for (int nt = 0; nt < 4; ++nt) {
                const float* vpp = vp + (kt * 32 + hi * 8) * 64 + nt * 16 + c;
                bf16x8 bv;
#pragma unroll
                for (int j = 0; j < 8; ++j) bv[j] = f2bf(vpp[j * 64]);
#pragma unroll
                for (int mt = 0; mt < 4; ++mt)
                    Uacc[mt][nt] = __builtin_amdgcn_mfma_f32_16x16x32_bf16(ap2[mt][kt], bv, Uacc[mt][nt], 0, 0, 0);
            }
        }
        __syncthreads();
    }
#pragma unroll
    for (int mt = 0; mt < 4; ++mt)
#pragma unroll
        for (int nt = 0; nt < 4; ++nt)
#pragma unroll
            for (int r = 0; r < 4; ++r)
                lds.U[mt * 16 + hi * 4 + r][w * 64 + nt * 16 + c] =
                    (unsigned short)f2bf(Uacc[mt][nt][r]);
    if (c == 0) {
#pragma unroll
        for (int r = 0; r < 4; ++r) Llds[w * 16 + hi * 4 + r] = Lacc[r];
    }
    __syncthreads();
    const float* nsq = ws + bh * 16;
    const float* vsw = ws + 512 + bh * 256;
    const int dd = t & 63, rq = t >> 6;
    float sg[4][4], ssum[4], omp[4], ov[4];
    const float inv22 = 1.0f / nsq[10];
#pragma unroll
    for (int gi = 0; gi < 4; ++gi) {
        float ss = 0.f, os = 0.f, ovv = 0.f;
#pragma unroll
        for (int gj = 0; gj < 4; ++gj) {
            float sgv = sqrtf(nsq[gi * 4 + gj] * inv22);
            sg[gi][gj] = sgv;
            ss += sgv;
            float om = fmaxf(1.0f - sgv, 0.0f);
            os += om;
            ovv += om * vsw[gj * 64 + dd];
        }
        ssum[gi] = ss; omp[gi] = os * 1024.0f; ov[gi] = ovv;
    }
    float* attn_out = out + base;
    float* lse_out = out + (size_t)BH_TOT * SEQ * DIM + (size_t)bh * SEQ;
    for (int k = 0; k < 16; ++k) {
        const int r = k * 4 + rq;
        const float u0 = bf2f(lds.U[r][dd]);
        const float u1 = bf2f(lds.U[r][64 + dd]);
        const float u2 = bf2f(lds.U[r][128 + dd]);
        const float u3 = bf2f(lds.U[r][192 + dd]);
        const float Lr = Llds[r];
        const int orow = qt * 64 + r;
#pragma unroll
        for (int gi = 0; gi < 4; ++gi) {
            float num = ov[gi] + sg[gi][0] * u0 + sg[gi][1] * u1 + sg[gi][2] * u2 + sg[gi][3] * u3;
            float den = omp[gi] + ssum[gi] * Lr;
            attn_out[(size_t)(gi * 1024 + orow) * 64 + dd] = num / den;
            if (dd == gi) lse_out[gi * 1024 + orow] = __logf(den);
        }
    }
}

extern "C" void kernel_launch(void* const* d_in, const int* in_sizes, int n_in,
                              void* d_out, int out_size, void* d_ws, size_t ws_size,
                              hipStream_t stream)
{
    (void)in_sizes; (void)n_in; (void)out_size;
    const float* query = (const float*)d_in[0];
    const float* key   = (const float*)d_in[1];
    const float* value = (const float*)d_in[2];
    float* ws   = (float*)d_ws;
    char*  wsb  = (char*)d_ws;
    float* outp = (float*)d_out;

    if (ws_size >= WS_NEED) {
        (void)hipMemsetAsync(d_ws, 0, QB_OFF, stream);   // zero nsq + vsum
        mega_prep<<<3584, 256, 0, stream>>>(query, key, value, ws, wsb);
        kattn4<<<1024, 256, 0, stream>>>(wsb, outp);
    } else {
        prep_norm2<<<128, 256, 0, stream>>>(query, key, ws);
        prep_vsum<<<128, 256, 0, stream>>>(value, ws);
        kattn_fallback<<<512, 256, 0, stream>>>(query, key, value, ws, outp);
    }
}